// Round 3
// baseline (588.976 us; speedup 1.0000x reference)
//
#include <hip/hip_runtime.h>
#include <math.h>

#define H 1024
#define V 50257
#define L 512
#define NBLK 512
#define NTHR 256
#define STAGE_ROWS 12

// ws float offsets
#define WS_ATTN   0        // 1024 attn_applied accumulator (zeroed by memset)
#define WS_CTR    1024     // 40 ints: 5 barriers x 8 sub-counters (zeroed)
#define WS_GS     1064     // global vocab exp-sum (zeroed)
#define WS_LOGITS 1072     // 512 attn logits
#define WS_X      1600     // 1024 combine output
#define WS_H      2624     // 1024 new h
#define WS_VLOG   4096     // 50257 vocab logits
#define MEMSET_BYTES 4288  // zeroes float indices [0,1072)

#define AS1 __attribute__((address_space(1)))
#define AS3 __attribute__((address_space(3)))

__device__ __forceinline__ float wave_sum(float v) {
    for (int o = 32; o > 0; o >>= 1) v += __shfl_down(v, o, 64);
    return v;
}
__device__ __forceinline__ float sigf(float x) { return 1.0f / (1.0f + expf(-x)); }
__device__ __forceinline__ float dot4(float4 a, float4 b) {
    return a.x * b.x + a.y * b.y + a.z * b.z + a.w * b.w;
}
// agent-scope (device) coherent-point load/store for cross-block intermediates
__device__ __forceinline__ float aload(const float* p) {
    return __hip_atomic_load(p, __ATOMIC_RELAXED, __HIP_MEMORY_SCOPE_AGENT);
}
__device__ __forceinline__ void astore(float* p, float v) {
    __hip_atomic_store(p, v, __ATOMIC_RELAXED, __HIP_MEMORY_SCOPE_AGENT);
}
__device__ __forceinline__ void gld_lds16(const float* g, float* l) {
    __builtin_amdgcn_global_load_lds((const AS1 void*)g, (AS3 void*)l, 16, 0, 0);
}

// all-block spin barrier: 8 sub-counters to spread atomic contention.
__device__ __forceinline__ void gbarrier(int* ctrbase, int k, int bid) {
    int* ctr = ctrbase + k * 8;
    __syncthreads();
    if (threadIdx.x == 0) {
        __threadfence();
        __hip_atomic_fetch_add(&ctr[bid & 7], 1, __ATOMIC_RELEASE, __HIP_MEMORY_SCOPE_AGENT);
        int sum;
        do {
            sum = 0;
            for (int i = 0; i < 8; ++i)
                sum += __hip_atomic_load(&ctr[i], __ATOMIC_ACQUIRE, __HIP_MEMORY_SCOPE_AGENT);
            if (sum < NBLK) __builtin_amdgcn_s_sleep(8);
        } while (sum < NBLK);
    }
    __syncthreads();
}

__global__ __launch_bounds__(NTHR, 3) void fused_decoder(
        const int* __restrict__ tok, const float* __restrict__ hidden,
        const float* __restrict__ enc, const float* __restrict__ emb,
        const float* __restrict__ attn_W, const float* __restrict__ attn_b,
        const float* __restrict__ comb_W, const float* __restrict__ comb_b,
        const float* __restrict__ W_ih, const float* __restrict__ W_hh,
        const float* __restrict__ b_ih, const float* __restrict__ b_hh,
        const float* __restrict__ out_W, const float* __restrict__ out_b,
        float* __restrict__ ws, float* __restrict__ out) {
    const int bid = blockIdx.x, t = threadIdx.x;
    const int w = t >> 6, l = t & 63;
    int* ctrbase = (int*)(ws + WS_CTR);

    __shared__ float4 staged4[STAGE_ROWS * 256];   // 48 KB: first 12 vocab rows
    __shared__ float red[8];
    __shared__ float wl[16];
    __shared__ float gsh[8];
    __shared__ float bsh[2];

    // block's vocab row range (98 rows + 1 extra for first 81 blocks)
    const int row0 = bid * 98 + (bid < 81 ? bid : 81);
    const int cnt  = 98 + (bid < 81 ? 1 : 0);

    // ---- stage first 12 vocab rows into LDS (overlaps with chain below) ----
#pragma unroll
    for (int r = 0; r < STAGE_ROWS; ++r) {
        const float* src = out_W + (size_t)(row0 + r) * H + w * 256 + l * 4;
        float* dst = (float*)&staged4[r * 256 + w * 64];  // wave-uniform base
        gld_lds16(src, dst);
    }

    const size_t token = (size_t)tok[0];
    const float4* ev4 = (const float4*)(emb + token * H);
    const float4* hv4 = (const float4*)hidden;

    // ---- P1: attn logit for row bid ----
    {
        const float4* rw = (const float4*)(attn_W + (size_t)bid * 2 * H);
        float acc = dot4(ev4[t], rw[t]) + dot4(hv4[t], rw[256 + t]);
        float s = wave_sum(acc);
        if (l == 0) red[w] = s;
        __syncthreads();
        if (t == 0)
            astore(ws + WS_LOGITS + bid, red[0] + red[1] + red[2] + red[3] + attn_b[bid]);
    }
    gbarrier(ctrbase, 0, bid);

    // ---- P2: softmax (no max-sub; logits bounded) + attn_applied ----
    if (bid < 128) {
        int jb = bid >> 5, lc = bid & 31;
        float e = expf(aload(ws + WS_LOGITS + t)) + expf(aload(ws + WS_LOGITS + 256 + t));
        float s = wave_sum(e);
        if (l == 0) red[w] = s;
        __syncthreads();
        if (t == 0) bsh[0] = red[0] + red[1] + red[2] + red[3];
        __syncthreads();
        float bs = bsh[0];
        if (t < 16) wl[t] = expf(aload(ws + WS_LOGITS + lc * 16 + t)) / bs;
        if (lc == 0 && t < 128)
            out[V + 2 * H + jb * 128 + t] = expf(aload(ws + WS_LOGITS + jb * 128 + t)) / bs;
        __syncthreads();
        int j = jb * 256 + t;
        float acc = 0.f;
#pragma unroll
        for (int i = 0; i < 16; ++i)
            acc += wl[i] * enc[(size_t)(lc * 16 + i) * H + j];
        atomicAdd(&ws[WS_ATTN + j], acc);
    }
    gbarrier(ctrbase, 1, bid);

    // ---- P3: combine + relu (blocks 0..255, wave per row) ----
    if (bid < 256) {
        int row = bid * 4 + w;
        float4 av[4];
#pragma unroll
        for (int i = 0; i < 4; ++i) {
            int base = (i * 64 + l) * 4;
            av[i].x = aload(ws + WS_ATTN + base);
            av[i].y = aload(ws + WS_ATTN + base + 1);
            av[i].z = aload(ws + WS_ATTN + base + 2);
            av[i].w = aload(ws + WS_ATTN + base + 3);
        }
        const float4* cw = (const float4*)comb_W;
        float acc = 0.f;
#pragma unroll
        for (int i = 0; i < 4; ++i) {
            acc += dot4(cw[(size_t)row * 512 + i * 64 + l], ev4[i * 64 + l]);
            acc += dot4(cw[(size_t)row * 512 + 256 + i * 64 + l], av[i]);
        }
        float s = wave_sum(acc);
        if (l == 0) astore(ws + WS_X + row, fmaxf(s + comb_b[row], 0.0f));
    }
    gbarrier(ctrbase, 2, bid);

    // ---- P4: gates + LSTM pointwise (all blocks; 2 n-units each; wave=gate) ----
    {
        int n0 = bid * 2, n1 = bid * 2 + 1;
        float4 x4[4];
#pragma unroll
        for (int i = 0; i < 4; ++i) {
            int base = (i * 64 + l) * 4;
            x4[i].x = aload(ws + WS_X + base);
            x4[i].y = aload(ws + WS_X + base + 1);
            x4[i].z = aload(ws + WS_X + base + 2);
            x4[i].w = aload(ws + WS_X + base + 3);
        }
        const float4* wi = (const float4*)W_ih;
        const float4* wh = (const float4*)W_hh;
#pragma unroll
        for (int u = 0; u < 2; ++u) {
            int row = w * H + (u == 0 ? n0 : n1);
            float acc = 0.f;
#pragma unroll
            for (int i = 0; i < 4; ++i) {
                acc += dot4(wi[(size_t)row * 256 + i * 64 + l], x4[i]);
                acc += dot4(wh[(size_t)row * 256 + i * 64 + l], hv4[i * 64 + l]);
            }
            float s = wave_sum(acc);
            if (l == 0) gsh[w * 2 + u] = s + b_ih[row] + b_hh[row];
        }
        __syncthreads();
        if (t < 2) {
            int n = bid * 2 + t;
            float gi = gsh[0 * 2 + t], gf = gsh[1 * 2 + t];
            float gg = gsh[2 * 2 + t], go = gsh[3 * 2 + t];
            float c0 = hidden[n];
            float c = sigf(gf) * c0 + sigf(gi) * tanhf(gg);
            float h = sigf(go) * tanhf(c);
            astore(ws + WS_H + n, h);
            out[V + n] = h;
            out[V + H + n] = c;
        }
    }
    gbarrier(ctrbase, 3, bid);

    // ---- P5: vocab logits (12 rows from LDS, rest from HBM) + global LSE ----
    {
        // staged LDS data must have landed
        asm volatile("s_waitcnt vmcnt(0)" ::: "memory");
        __syncthreads();
        float4 hr[4];
#pragma unroll
        for (int i = 0; i < 4; ++i) {
            int base = (i * 64 + l) * 4;
            hr[i].x = aload(ws + WS_H + base);
            hr[i].y = aload(ws + WS_H + base + 1);
            hr[i].z = aload(ws + WS_H + base + 2);
            hr[i].w = aload(ws + WS_H + base + 3);
        }
        const float4* ow = (const float4*)out_W;
        float sw = 0.f;  // lane-0 partial exp-sum per wave
        for (int j = w; j < cnt; j += 4) {
            int row = row0 + j;
            float acc = 0.f;
            if (j < STAGE_ROWS) {
#pragma unroll
                for (int i = 0; i < 4; ++i)
                    acc += dot4(staged4[j * 256 + i * 64 + l], hr[i]);
            } else {
#pragma unroll
                for (int i = 0; i < 4; ++i)
                    acc += dot4(ow[(size_t)row * 256 + i * 64 + l], hr[i]);
            }
            float s = wave_sum(acc);
            if (l == 0) {
                float logit = s + out_b[row];
                ws[WS_VLOG + row] = logit;   // self-read later by this block
                sw += expf(logit);
            }
        }
        if (l == 0) red[w] = sw;
        __syncthreads();
        if (t == 0) {
            float sb = red[0] + red[1] + red[2] + red[3];
            __hip_atomic_fetch_add(ws + WS_GS, sb, __ATOMIC_RELAXED, __HIP_MEMORY_SCOPE_AGENT);
        }
    }
    gbarrier(ctrbase, 4, bid);
    {
        if (t == 0) bsh[1] = logf(aload(ws + WS_GS));
        __syncthreads();
        float lse = bsh[1];
        for (int i = t; i < cnt; i += NTHR)
            out[row0 + i] = ws[WS_VLOG + row0 + i] - lse;
    }
}

extern "C" void kernel_launch(void* const* d_in, const int* in_sizes, int n_in,
                              void* d_out, int out_size, void* d_ws, size_t ws_size,
                              hipStream_t stream) {
    const int*   tok     = (const int*)d_in[0];
    const float* hidden  = (const float*)d_in[1];
    const float* enc     = (const float*)d_in[2];
    const float* emb     = (const float*)d_in[3];
    const float* attn_W  = (const float*)d_in[4];
    const float* attn_b  = (const float*)d_in[5];
    const float* comb_W  = (const float*)d_in[6];
    const float* comb_b  = (const float*)d_in[7];
    const float* W_ih    = (const float*)d_in[8];
    const float* W_hh    = (const float*)d_in[9];
    const float* b_ih    = (const float*)d_in[10];
    const float* b_hh    = (const float*)d_in[11];
    const float* out_W   = (const float*)d_in[12];
    const float* out_b   = (const float*)d_in[13];
    float* out = (float*)d_out;
    float* ws  = (float*)d_ws;

    // zero attn accumulator + barrier counters + global exp-sum each replay
    hipMemsetAsync(ws, 0, MEMSET_BYTES, stream);
    fused_decoder<<<NBLK, NTHR, 0, stream>>>(tok, hidden, enc, emb, attn_W, attn_b,
                                             comb_W, comb_b, W_ih, W_hh, b_ih, b_hh,
                                             out_W, out_b, ws, out);
}

// Round 4
// 64.444 us; speedup vs baseline: 9.1393x; 9.1393x over previous
//
#include <hip/hip_runtime.h>
#include <math.h>

#define H 1024
#define V 50257
#define L 512
#define NPART 1571   // ceil(V/32) vocab blocks

// ws float offsets
#define WS_LOGITS 0                 // 512 attn logits
#define WS_ATTN   512               // 1024 attn_applied (atomic accum, zeroed by kA)
#define WS_X      1536              // 1024 combine output
#define WS_H      2560              // 1024 new h
#define WS_VLOG   3584              // 50257 vocab logits
#define WS_PART   53844             // NPART*2 online-softmax partials (m,s)

__device__ __forceinline__ float wave_sum(float v) {
    for (int o = 32; o > 0; o >>= 1) v += __shfl_down(v, o, 64);
    return v;
}
__device__ __forceinline__ float sigf(float x) { return 1.0f / (1.0f + expf(-x)); }
__device__ __forceinline__ float dot4(float4 a, float4 b) {
    return a.x * b.x + a.y * b.y + a.z * b.z + a.w * b.w;
}
__device__ __forceinline__ void osm_merge(float& m, float& s, float m2, float s2) {
    float M = fmaxf(m, m2);
    if (M == -INFINITY) { m = M; s = 0.f; return; }
    s = s * expf(m - M) + s2 * expf(m2 - M);
    m = M;
}

// kA: attn_logits[r] = dot(concat(embedded, h0), attn_W[r]) + attn_b[r]
// grid 512 x 256. Blocks 0..3 also zero the attn accumulator for kB.
__global__ void kA_attn_logits(const int* __restrict__ tok,
                               const float* __restrict__ hidden,
                               const float* __restrict__ emb,
                               const float* __restrict__ attn_W,
                               const float* __restrict__ attn_b,
                               float* __restrict__ ws) {
    int r = blockIdx.x, t = threadIdx.x;
    if (r < 4) ws[WS_ATTN + r * 256 + t] = 0.0f;
    size_t token = (size_t)tok[0];
    const float4* rw = (const float4*)(attn_W + (size_t)r * 2 * H);
    const float4* ev = (const float4*)(emb + token * H);
    const float4* hv = (const float4*)hidden;
    float acc = dot4(ev[t], rw[t]) + dot4(hv[t], rw[256 + t]);
    float s = wave_sum(acc);
    __shared__ float red[4];
    if ((t & 63) == 0) red[t >> 6] = s;
    __syncthreads();
    if (t == 0) ws[WS_LOGITS + r] = red[0] + red[1] + red[2] + red[3] + attn_b[r];
}

// kB: fused softmax + attn_applied. grid 128 x 256.
__global__ void kB_softmax_attn(const float* __restrict__ enc,
                                float* __restrict__ ws,
                                float* __restrict__ out) {
    int t = threadIdx.x, bid = blockIdx.x;
    int jb = bid >> 5, lc = bid & 31;
    float v0 = ws[WS_LOGITS + t];
    float v1 = ws[WS_LOGITS + 256 + t];
    float m = fmaxf(v0, v1);
    for (int o = 32; o > 0; o >>= 1) m = fmaxf(m, __shfl_down(m, o, 64));
    __shared__ float red[4];
    __shared__ float bm, bs;
    if ((t & 63) == 0) red[t >> 6] = m;
    __syncthreads();
    if (t == 0) bm = fmaxf(fmaxf(red[0], red[1]), fmaxf(red[2], red[3]));
    __syncthreads();
    float e = expf(v0 - bm) + expf(v1 - bm);
    float s = wave_sum(e);
    if ((t & 63) == 0) red[t >> 6] = s;
    __syncthreads();
    if (t == 0) bs = red[0] + red[1] + red[2] + red[3];
    __syncthreads();
    __shared__ float wl[16];
    int l0 = lc * 16;
    if (t < 16) wl[t] = expf(ws[WS_LOGITS + l0 + t] - bm) / bs;
    if (lc == 0 && t < 128) {
        int l = jb * 128 + t;
        out[V + 2 * H + l] = expf(ws[WS_LOGITS + l] - bm) / bs;
    }
    __syncthreads();
    int j = jb * 256 + t;
    float acc = 0.f;
#pragma unroll
    for (int i = 0; i < 16; ++i)
        acc += wl[i] * enc[(size_t)(l0 + i) * H + j];
    atomicAdd(&ws[WS_ATTN + j], acc);
}

// kC: x[i] = relu(dot(concat(embedded, attn_applied), comb_W[i]) + comb_b[i])
// grid 64 x 256 (4 waves x 4 rows each = 16 rows/block)
__global__ void kC_combine(const int* __restrict__ tok,
                           const float* __restrict__ emb,
                           const float* __restrict__ comb_W,
                           const float* __restrict__ comb_b,
                           float* __restrict__ ws) {
    int t = threadIdx.x;
    int w = t >> 6, l = t & 63;
    size_t token = (size_t)tok[0];
    __shared__ float4 vec4[512];
    vec4[t] = ((const float4*)(emb + token * H))[t];
    vec4[256 + t] = ((const float4*)(ws + WS_ATTN))[t];
    __syncthreads();
    const float4* cw = (const float4*)comb_W;
#pragma unroll
    for (int rr = 0; rr < 4; ++rr) {
        int r = blockIdx.x * 16 + w * 4 + rr;
        float acc = 0.f;
#pragma unroll
        for (int i = 0; i < 8; ++i)
            acc += dot4(cw[(size_t)r * 512 + i * 64 + l], vec4[i * 64 + l]);
        float s = wave_sum(acc);
        if (l == 0) ws[WS_X + r] = fmaxf(s + comb_b[r], 0.0f);
    }
}

// kD: fused gates + LSTM pointwise. grid 512 x 256.
// Block owns units n = bid*2 + {0,1}. Wave w: unit u=w>>1, gate pair gp=w&1.
// Two independent accumulators per wave -> 16 float4 loads in flight.
__global__ void kD_gates_lstm(const float* __restrict__ hidden,
                              const float* __restrict__ W_ih,
                              const float* __restrict__ W_hh,
                              const float* __restrict__ b_ih,
                              const float* __restrict__ b_hh,
                              float* __restrict__ ws,
                              float* __restrict__ out) {
    int t = threadIdx.x;
    int w = t >> 6, l = t & 63;
    __shared__ float4 xs[256], hs[256];
    xs[t] = ((const float4*)(ws + WS_X))[t];
    hs[t] = ((const float4*)hidden)[t];
    __syncthreads();
    int u = w >> 1, gp = w & 1;
    int n = blockIdx.x * 2 + u;
    int row0 = (gp * 2) * H + n;       // gates: 0=i,1=f (gp=0); 2=g,3=o (gp=1)
    int row1 = (gp * 2 + 1) * H + n;
    const float4* wi = (const float4*)W_ih;
    const float4* wh = (const float4*)W_hh;
    float a0 = 0.f, a1 = 0.f;
#pragma unroll
    for (int i = 0; i < 4; ++i) {
        float4 x4 = xs[i * 64 + l], h4 = hs[i * 64 + l];
        a0 += dot4(wi[(size_t)row0 * 256 + i * 64 + l], x4);
        a0 += dot4(wh[(size_t)row0 * 256 + i * 64 + l], h4);
        a1 += dot4(wi[(size_t)row1 * 256 + i * 64 + l], x4);
        a1 += dot4(wh[(size_t)row1 * 256 + i * 64 + l], h4);
    }
    float s0 = wave_sum(a0);
    float s1 = wave_sum(a1);
    __shared__ float gsh[2][4];
    if (l == 0) {
        gsh[u][gp * 2]     = s0 + b_ih[row0] + b_hh[row0];
        gsh[u][gp * 2 + 1] = s1 + b_ih[row1] + b_hh[row1];
    }
    __syncthreads();
    if (t < 2) {
        int nn = blockIdx.x * 2 + t;
        float gi = gsh[t][0], gf = gsh[t][1], gg = gsh[t][2], go = gsh[t][3];
        float c0 = hidden[nn];
        float c = sigf(gf) * c0 + sigf(gi) * tanhf(gg);
        float h = sigf(go) * tanhf(c);
        ws[WS_H + nn] = h;
        out[V + nn] = h;
        out[V + H + nn] = c;
    }
}

// kE: vocab logits + per-block online-softmax partial. grid 1571 x 256.
// 8 rows/wave processed as 4 pairs with independent accumulators.
__global__ void kE_vocab(const float* __restrict__ out_W,
                         const float* __restrict__ out_b,
                         float* __restrict__ ws) {
    int t = threadIdx.x;
    int w = t >> 6, l = t & 63;
    const float4* h4 = (const float4*)(ws + WS_H);
    float4 hr[4];
#pragma unroll
    for (int i = 0; i < 4; ++i) hr[i] = h4[i * 64 + l];
    const float4* ow = (const float4*)out_W;
    float pm = -INFINITY, psv = 0.f;
#pragma unroll
    for (int rp = 0; rp < 4; ++rp) {
        int r0 = blockIdx.x * 32 + w * 8 + rp * 2;
        int r1 = r0 + 1;
        bool v0 = r0 < V, v1 = r1 < V;
        size_t q0 = (size_t)(v0 ? r0 : V - 1) * 256;
        size_t q1 = (size_t)(v1 ? r1 : V - 1) * 256;
        float a0 = 0.f, a1 = 0.f;
#pragma unroll
        for (int i = 0; i < 4; ++i) {
            a0 += dot4(ow[q0 + i * 64 + l], hr[i]);
            a1 += dot4(ow[q1 + i * 64 + l], hr[i]);
        }
        float s0 = wave_sum(a0);
        float s1 = wave_sum(a1);
        if (l == 0) {
            if (v0) {
                float lg = s0 + out_b[r0];
                ws[WS_VLOG + r0] = lg;
                float M = fmaxf(pm, lg);
                psv = psv * expf(pm - M) + expf(lg - M);
                pm = M;
            }
            if (v1) {
                float lg = s1 + out_b[r1];
                ws[WS_VLOG + r1] = lg;
                float M = fmaxf(pm, lg);
                psv = psv * expf(pm - M) + expf(lg - M);
                pm = M;
            }
        }
    }
    __shared__ float sm[4], ss[4];
    if (l == 0) { sm[w] = pm; ss[w] = psv; }
    __syncthreads();
    if (t == 0) {
        float m = sm[0], s = ss[0];
        for (int i = 1; i < 4; ++i) osm_merge(m, s, sm[i], ss[i]);
        ws[WS_PART + 2 * blockIdx.x] = m;
        ws[WS_PART + 2 * blockIdx.x + 1] = s;
    }
}

// kF: every block redundantly reduces the 1571 partials (L2-resident),
// then writes its 256-row output slice. grid 197 x 256.
__global__ void kF_logsoftmax(const float* __restrict__ ws,
                              float* __restrict__ out) {
    int t = threadIdx.x;
    float m = -INFINITY, s = 0.f;
    for (int i = t; i < NPART; i += 256)
        osm_merge(m, s, ws[WS_PART + 2 * i], ws[WS_PART + 2 * i + 1]);
    for (int o = 32; o > 0; o >>= 1) {
        float m2 = __shfl_down(m, o, 64);
        float s2 = __shfl_down(s, o, 64);
        osm_merge(m, s, m2, s2);
    }
    __shared__ float sm[4], ss[4];
    __shared__ float lse;
    if ((t & 63) == 0) { sm[t >> 6] = m; ss[t >> 6] = s; }
    __syncthreads();
    if (t == 0) {
        float mm = sm[0], sv = ss[0];
        for (int i = 1; i < 4; ++i) osm_merge(mm, sv, sm[i], ss[i]);
        lse = mm + logf(sv);
    }
    __syncthreads();
    int r = blockIdx.x * 256 + t;
    if (r < V) out[r] = ws[WS_VLOG + r] - lse;
}

extern "C" void kernel_launch(void* const* d_in, const int* in_sizes, int n_in,
                              void* d_out, int out_size, void* d_ws, size_t ws_size,
                              hipStream_t stream) {
    const int*   tok     = (const int*)d_in[0];
    const float* hidden  = (const float*)d_in[1];
    const float* enc     = (const float*)d_in[2];
    const float* emb     = (const float*)d_in[3];
    const float* attn_W  = (const float*)d_in[4];
    const float* attn_b  = (const float*)d_in[5];
    const float* comb_W  = (const float*)d_in[6];
    const float* comb_b  = (const float*)d_in[7];
    const float* W_ih    = (const float*)d_in[8];
    const float* W_hh    = (const float*)d_in[9];
    const float* b_ih    = (const float*)d_in[10];
    const float* b_hh    = (const float*)d_in[11];
    const float* out_W   = (const float*)d_in[12];
    const float* out_b   = (const float*)d_in[13];
    float* out = (float*)d_out;
    float* ws  = (float*)d_ws;

    kA_attn_logits<<<512, 256, 0, stream>>>(tok, hidden, emb, attn_W, attn_b, ws);
    kB_softmax_attn<<<128, 256, 0, stream>>>(enc, ws, out);
    kC_combine<<<64, 256, 0, stream>>>(tok, emb, comb_W, comb_b, ws);
    kD_gates_lstm<<<512, 256, 0, stream>>>(hidden, W_ih, W_hh, b_ih, b_hh, ws, out);
    kE_vocab<<<1571, 256, 0, stream>>>(out_W, out_b, ws);
    kF_logsoftmax<<<197, 256, 0, stream>>>(ws, out);
}